// Round 14
// baseline (272.993 us; speedup 1.0000x reference)
//
#include <hip/hip_runtime.h>
#include <hip/hip_bf16.h>

#define B_ 32
#define T_ 64
#define H_ 128
#define L3OUT 54
#define FLAT_ 1728

typedef __attribute__((ext_vector_type(8))) short bf16x8;
typedef __attribute__((ext_vector_type(4))) float f32x4;

__device__ __forceinline__ float leakyf(float v) { return v > 0.f ? v : 0.01f * v; }
__device__ __forceinline__ float sigmoidf_(float v) { return 1.f / (1.f + expf(-v)); }
__device__ __forceinline__ unsigned int bf16rne(float v) {
  unsigned int b = __float_as_uint(v);
  return (b + 0x7FFFu + ((b >> 16) & 1u)) >> 16;
}
__device__ __forceinline__ unsigned int pk2bf(float lo, float hi) {
  __hip_bfloat162 h2 = __float22bfloat162_rn(make_float2(lo, hi));  // v_cvt_pk_bf16_f32, RNE
  return *reinterpret_cast<unsigned int*>(&h2);
}
__device__ __forceinline__ bf16x8 ldb8(const unsigned short* p) {
  return *(const bf16x8*)p;
}
// LDS-only barrier: global loads stay in flight across it (consumers get
// compiler-inserted vmcnt waits). All cross-thread deps here are LDS.
__device__ __forceinline__ void barrier_lgkm() {
  asm volatile("s_waitcnt lgkmcnt(0)\n\ts_barrier" ::: "memory");
}

// ---------------------------------------------------------------------------
// Kernel 0: weight prep + transposes. (unchanged)
// ---------------------------------------------------------------------------
__global__ __launch_bounds__(256) void k_prep(
    const float* __restrict__ w1, const float* __restrict__ w2,
    const float* __restrict__ w3, const float* __restrict__ linw,
    const float* __restrict__ wih0, const float* __restrict__ whh0,
    const float* __restrict__ wih1, const float* __restrict__ whh1,
    unsigned short* __restrict__ w1eh, unsigned short* __restrict__ w1el,
    unsigned short* __restrict__ w2h, unsigned short* __restrict__ w2l,
    unsigned short* __restrict__ w3h, unsigned short* __restrict__ w3l,
    unsigned short* __restrict__ linwh, unsigned short* __restrict__ linwl,
    unsigned short* __restrict__ wih0h, unsigned short* __restrict__ wih0l,
    float* __restrict__ whh0T, float* __restrict__ wih1T,
    float* __restrict__ whh1T) {
  const int e = blockIdx.x * 256 + threadIdx.x;
  if (e >= 264960) {
    int e5 = e - 264960;
    int m = e5 >> 16, r = e5 & 65535;
    int k = r >> 9, j = r & 511;
    const float* src = (m == 0) ? whh0 : ((m == 1) ? wih1 : whh1);
    float* dst = (m == 0) ? whh0T : ((m == 1) ? wih1T : whh1T);
    dst[r] = src[j * 128 + k];
    return;
  }
  float v;
  unsigned short* dh;
  unsigned short* dl;
  int di;
  if (e < 20480) {
    int cc = e / 5120, rem = e - cc * 5120;
    int c2 = rem / 160, r = rem - c2 * 160;
    int tap = r >> 5, c1l = r & 31;
    v = w2[c2 * 640 + (cc * 32 + c1l) * 5 + tap];
    dh = w2h; dl = w2l; di = e;
  } else if (e < 25600) {
    int e2 = e - 20480;
    int c3 = e2 / 160, r = e2 - c3 * 160;
    int tap = r >> 5, c2 = r & 31;
    v = w3[c3 * 160 + c2 * 5 + tap];
    dh = w3h; dl = w3l; di = e2;
  } else if (e < 198400) {
    int e3 = e - 25600;
    v = linw[e3];
    dh = linwh; dl = linwl; di = e3;
  } else if (e < 263936) {
    int e4 = e - 198400;
    int g = e4 >> 7, k = e4 & 127;
    v = (k < 100) ? wih0[g * 100 + k] : 0.f;
    dh = wih0h; dl = wih0l; di = e4;
  } else {
    int i = e - 263936;
    int c1 = i >> 3, j = i & 7;
    v = (j < 5) ? w1[c1 * 5 + j] : 0.f;
    dh = w1eh; dl = w1el; di = i;
  }
  unsigned int hb = bf16rne(v);
  float hf = __uint_as_float(hb << 16);
  unsigned int lb = bf16rne(v - hf);
  dh[di] = (unsigned short)hb;
  dl[di] = (unsigned short)lb;
}

// ---------------------------------------------------------------------------
// Kernel 1: conv1 (fp32) + conv2 (MFMA) + conv3 (MFMA). Round-12 structure +
// NEW: explicit weight-fragment latency pipelining --
//  (a) chunk-lead: tap-0 frags issued BEFORE the conv1 phase (latency hides
//      under conv1 VALU + lgkm barrier, loads stay in flight);
//  (b) tap-pipeline: tap t+1 frags prefetched during tap t's MFMAs;
//  (c) cc loop unrolled; conv3 frags double-buffered the same way.
// __launch_bounds__(512, 4): allow VGPR up to 128 for the load pipeline.
// ---------------------------------------------------------------------------
__global__ __launch_bounds__(512, 4) void k_conv123(
    const float* __restrict__ X, const float* __restrict__ w1,
    const unsigned short* __restrict__ w2h, const unsigned short* __restrict__ w2l,
    const unsigned short* __restrict__ w3h, const unsigned short* __restrict__ w3l,
    unsigned short* __restrict__ s3g) {
  __shared__ __align__(16) float Xs[1504];
  __shared__ __align__(16) unsigned int AhU[10640];  // [532 rows][20 u32]

  const int n = blockIdx.x;
  const int tid = threadIdx.x;
  const int lane = tid & 63;
  const int w = tid >> 6;        // 0..7
  const int l15 = lane & 15;
  const int cg = lane >> 4;

  const float* Xn = X + (size_t)n * 1500;
  for (int i = tid; i < 1500; i += 512) Xs[i] = Xn[i];
  if (tid < 4) Xs[1500 + tid] = 0.f;
  for (int i = tid; i < 640; i += 512) AhU[10000 + i] = 0u;  // rows 500..531
  barrier_lgkm();

  // hoisted conv1 window (position = tid)
  float x0 = 0.f, x1 = 0.f, x2 = 0.f, x3 = 0.f, x4 = 0.f;
  if (tid < 500) {
    const float* xp = Xs + 3 * tid;
    x0 = xp[0]; x1 = xp[1]; x2 = xp[2]; x3 = xp[3]; x4 = xp[4];
  }

  f32x4 acc2[2][2];
#pragma unroll
  for (int a = 0; a < 2; ++a)
#pragma unroll
    for (int m = 0; m < 2; ++m) acc2[a][m] = (f32x4){0.f, 0.f, 0.f, 0.f};

#pragma unroll
  for (int cc = 0; cc < 4; ++cc) {  // 4 chunks of 32 c1 (unrolled)
    const unsigned short* w2hB = w2h + cc * 5120;
    const unsigned short* w2lB = w2l + cc * 5120;
    // (a) chunk-lead: tap-0 frags -- in flight across barrier + conv1 phase
    bf16x8 fh0 = ldb8(w2hB + l15 * 160 + cg * 8);
    bf16x8 fh1 = ldb8(w2hB + (l15 + 16) * 160 + cg * 8);
    bf16x8 fl0 = ldb8(w2lB + l15 * 160 + cg * 8);
    bf16x8 fl1 = ldb8(w2lB + (l15 + 16) * 160 + cg * 8);
    barrier_lgkm();                 // previous chunk's conv2 reads done
    // ---- conv1: all 32 c1 of this chunk for position tid ----
    if (tid < 500) {
      const float* wc = w1 + cc * 160;  // uniform address -> s_load
      unsigned int rowbuf[16];
#pragma unroll
      for (int p = 0; p < 16; ++p) {
        const float* wa = wc + 10 * p;
        float vA = fmaf(x4, wa[4], fmaf(x3, wa[3], fmaf(x2, wa[2], fmaf(x1, wa[1], x0 * wa[0]))));
        float vB = fmaf(x4, wa[9], fmaf(x3, wa[8], fmaf(x2, wa[7], fmaf(x1, wa[6], x0 * wa[5]))));
        vA = fmaxf(vA, 0.01f * vA);  // leaky == max(v, 0.01v)
        vB = fmaxf(vB, 0.01f * vB);
        rowbuf[p] = pk2bf(vA, vB);
      }
#pragma unroll
      for (int q = 0; q < 4; ++q)
        *(uint4*)(&AhU[tid * 20 + 4 * q]) = *(uint4*)(&rowbuf[4 * q]);
    }
    barrier_lgkm();
    // ---- conv2 MFMA over this chunk, tap-pipelined frags ----
#pragma unroll
    for (int tap = 0; tap < 5; ++tap) {
      bf16x8 ah0 = fh0, ah1 = fh1, al0 = fl0, al1 = fl1;
      if (tap < 4) {  // (b) prefetch next tap's frags
        const int wc = (tap + 1) * 32 + cg * 8;
        fh0 = ldb8(w2hB + l15 * 160 + wc);
        fh1 = ldb8(w2hB + (l15 + 16) * 160 + wc);
        fl0 = ldb8(w2lB + l15 * 160 + wc);
        fl1 = ldb8(w2lB + (l15 + 16) * 160 + wc);
      }
      {  // n-tile w
        bf16x8 bfr = ldb8((const unsigned short*)AhU + (3 * (w * 16 + l15) + tap) * 40 + cg * 8);
        acc2[0][0] = __builtin_amdgcn_mfma_f32_16x16x32_bf16(ah0, bfr, acc2[0][0], 0, 0, 0);
        acc2[0][0] = __builtin_amdgcn_mfma_f32_16x16x32_bf16(al0, bfr, acc2[0][0], 0, 0, 0);
        acc2[0][1] = __builtin_amdgcn_mfma_f32_16x16x32_bf16(ah1, bfr, acc2[0][1], 0, 0, 0);
        acc2[0][1] = __builtin_amdgcn_mfma_f32_16x16x32_bf16(al1, bfr, acc2[0][1], 0, 0, 0);
      }
      if (w < 3) {  // n-tile 8+w
        int nt = 8 + w;
        bf16x8 bfr = ldb8((const unsigned short*)AhU + (3 * (nt * 16 + l15) + tap) * 40 + cg * 8);
        acc2[1][0] = __builtin_amdgcn_mfma_f32_16x16x32_bf16(ah0, bfr, acc2[1][0], 0, 0, 0);
        acc2[1][0] = __builtin_amdgcn_mfma_f32_16x16x32_bf16(al0, bfr, acc2[1][0], 0, 0, 0);
        acc2[1][1] = __builtin_amdgcn_mfma_f32_16x16x32_bf16(ah1, bfr, acc2[1][1], 0, 0, 0);
        acc2[1][1] = __builtin_amdgcn_mfma_f32_16x16x32_bf16(al1, bfr, acc2[1][1], 0, 0, 0);
      }
    }
  }
  // conv3 tap-0 frags: issue BEFORE the A3 epilogue (hide under A3 writes)
  bf16x8 c3h0, c3h1, c3l0, c3l1;
  if (w < 4) {
    c3h0 = ldb8(w3h + l15 * 160 + cg * 8);
    c3h1 = ldb8(w3h + (l15 + 16) * 160 + cg * 8);
    c3l0 = ldb8(w3l + l15 * 160 + cg * 8);
    c3l1 = ldb8(w3l + (l15 + 16) * 160 + cg * 8);
  }
  barrier_lgkm();  // all conv2 reads of AhU done
  // A3 (aliases AhU): rows = l2; zero pad rows 176..195
  for (int i = tid; i < 400; i += 512) AhU[176 * 20 + i] = 0u;
#pragma unroll
  for (int nti = 0; nti < 2; ++nti) {
    int nt = (nti == 0) ? w : (8 + w);
    if (nti == 0 || w < 3) {
      int l2 = nt * 16 + l15;
#pragma unroll
      for (int mt = 0; mt < 2; ++mt) {
#pragma unroll
        for (int j = 0; j < 2; ++j) {
          float e0 = leakyf(acc2[nti][mt][2 * j]);
          float e1 = leakyf(acc2[nti][mt][2 * j + 1]);
          AhU[l2 * 20 + mt * 8 + cg * 2 + j] = pk2bf(e0, e1);
        }
      }
    }
  }
  barrier_lgkm();
  // conv3 MFMA: waves 0..3 (l3 tile = w), tap-pipelined
  if (w < 4) {
    f32x4 a3[2];
    a3[0] = (f32x4){0.f, 0.f, 0.f, 0.f};
    a3[1] = (f32x4){0.f, 0.f, 0.f, 0.f};
#pragma unroll
    for (int tap = 0; tap < 5; ++tap) {
      bf16x8 wh0 = c3h0, wh1 = c3h1, wl0 = c3l0, wl1 = c3l1;
      if (tap < 4) {
        const int wc = (tap + 1) * 32 + cg * 8;
        c3h0 = ldb8(w3h + l15 * 160 + wc);
        c3h1 = ldb8(w3h + (l15 + 16) * 160 + wc);
        c3l0 = ldb8(w3l + l15 * 160 + wc);
        c3l1 = ldb8(w3l + (l15 + 16) * 160 + wc);
      }
      bf16x8 bfr = ldb8((const unsigned short*)AhU + (3 * (w * 16 + l15) + tap) * 40 + cg * 8);
      a3[0] = __builtin_amdgcn_mfma_f32_16x16x32_bf16(wh0, bfr, a3[0], 0, 0, 0);
      a3[0] = __builtin_amdgcn_mfma_f32_16x16x32_bf16(wl0, bfr, a3[0], 0, 0, 0);
      a3[1] = __builtin_amdgcn_mfma_f32_16x16x32_bf16(wh1, bfr, a3[1], 0, 0, 0);
      a3[1] = __builtin_amdgcn_mfma_f32_16x16x32_bf16(wl1, bfr, a3[1], 0, 0, 0);
    }
    int l3 = w * 16 + l15;
    if (l3 < L3OUT) {
#pragma unroll
      for (int mt = 0; mt < 2; ++mt) {
#pragma unroll
        for (int r = 0; r < 4; ++r) {
          int c3 = mt * 16 + cg * 4 + r;
          s3g[(size_t)n * FLAT_ + c3 * L3OUT + l3] = (unsigned short)bf16rne(leakyf(a3[mt][r]));
        }
      }
    }
  }
}

// ---------------------------------------------------------------------------
// Kernel 2: FUSED fe + xg0. (unchanged)
// ---------------------------------------------------------------------------
__global__ __launch_bounds__(448) void k_gemm_fx(
    const unsigned short* __restrict__ s3g,
    const unsigned short* __restrict__ linwh, const unsigned short* __restrict__ linwl,
    const unsigned short* __restrict__ wih0h, const unsigned short* __restrict__ wih0l,
    float* __restrict__ xg0) {
  __shared__ __align__(16) unsigned short fehS[16][136];
  __shared__ __align__(16) unsigned short felS[16][136];

  const int m0 = blockIdx.x * 16;
  const int tid = threadIdx.x;
  const int lane = tid & 63;
  const int w = tid >> 6;
  const int l15 = lane & 15;
  const int cg = lane >> 4;

  if (tid < 192) {
    int r = tid / 12, c = tid - r * 12;
    ((unsigned int*)&fehS[r][112])[c] = 0u;
    ((unsigned int*)&felS[r][112])[c] = 0u;
  }

  int brow = w * 16 + l15;
  if (brow > 99) brow = 99;
  const unsigned short* ap = s3g + (size_t)(m0 + l15) * FLAT_ + cg * 8;
  const unsigned short* bhp = linwh + (size_t)brow * FLAT_ + cg * 8;
  const unsigned short* blp = linwl + (size_t)brow * FLAT_ + cg * 8;

  f32x4 acc = (f32x4){0.f, 0.f, 0.f, 0.f};
#pragma unroll 6
  for (int ks = 0; ks < 54; ++ks) {
    bf16x8 af = ldb8(ap + ks * 32);
    bf16x8 bh = ldb8(bhp + ks * 32);
    bf16x8 bl = ldb8(blp + ks * 32);
    acc = __builtin_amdgcn_mfma_f32_16x16x32_bf16(af, bh, acc, 0, 0, 0);
    acc = __builtin_amdgcn_mfma_f32_16x16x32_bf16(af, bl, acc, 0, 0, 0);
  }
  const int jcol = w * 16 + l15;
#pragma unroll
  for (int r = 0; r < 4; ++r) {
    float v = acc[r];
    unsigned int hb = bf16rne(v);
    float hf = __uint_as_float(hb << 16);
    unsigned int lb = bf16rne(v - hf);
    fehS[cg * 4 + r][jcol] = (unsigned short)hb;
    felS[cg * 4 + r][jcol] = (unsigned short)lb;
  }
  __syncthreads();

#pragma unroll
  for (int nt0 = 0; nt0 < 5; ++nt0) {
    int nt = w + 7 * nt0;
    if (nt < 32) {
      f32x4 a = (f32x4){0.f, 0.f, 0.f, 0.f};
#pragma unroll
      for (int ks = 0; ks < 4; ++ks) {
        bf16x8 ah = ldb8(&fehS[l15][ks * 32 + cg * 8]);
        bf16x8 al = ldb8(&felS[l15][ks * 32 + cg * 8]);
        int br = nt * 16 + l15;
        bf16x8 bh = ldb8(wih0h + (size_t)br * 128 + ks * 32 + cg * 8);
        bf16x8 bl = ldb8(wih0l + (size_t)br * 128 + ks * 32 + cg * 8);
        a = __builtin_amdgcn_mfma_f32_16x16x32_bf16(ah, bh, a, 0, 0, 0);
        a = __builtin_amdgcn_mfma_f32_16x16x32_bf16(ah, bl, a, 0, 0, 0);
        a = __builtin_amdgcn_mfma_f32_16x16x32_bf16(al, bh, a, 0, 0, 0);
      }
#pragma unroll
      for (int r = 0; r < 4; ++r)
        xg0[(size_t)(m0 + cg * 4 + r) * 512 + nt * 16 + l15] = a[r];
    }
  }
}

// ---------------------------------------------------------------------------
// Kernel 3: LSTM layer 0. (unchanged from round 13)
// ---------------------------------------------------------------------------
__global__ __launch_bounds__(512) void k_lstm0(
    const float* __restrict__ xg0, const float* __restrict__ whh0T,
    const int* __restrict__ lengths, float* __restrict__ hs1) {
  __shared__ __align__(16) float h0s[H_];
  __shared__ float ps[16 * 128];
  __shared__ float gs[512];
  const int b = blockIdx.x;
  const int tid = threadIdx.x;
  const int ks = tid >> 7;
  const int jj = tid & 127;
  float w[4][32];
#pragma unroll
  for (int kk = 0; kk < 32; ++kk) {
#pragma unroll
    for (int q = 0; q < 4; ++q)
      w[q][kk] = whh0T[(ks * 32 + kk) * 512 + q * 128 + jj];
  }
  if (tid < H_) h0s[tid] = 0.f;
  float c = 0.f;
  const int len = lengths[b];
  float xcur = xg0[(size_t)(b * T_) * 512 + tid];
  barrier_lgkm();
  for (int t = 0; t < len; ++t) {
    float xnxt = (t + 1 < len) ? xg0[(size_t)(b * T_ + t + 1) * 512 + tid] : 0.f;
    float p0 = 0.f, p1 = 0.f, p2 = 0.f, p3 = 0.f;
#pragma unroll
    for (int k4 = 0; k4 < 8; ++k4) {
      float4 hv = *(const float4*)(h0s + ks * 32 + k4 * 4);
      p0 = fmaf(hv.x, w[0][k4 * 4], fmaf(hv.y, w[0][k4 * 4 + 1], fmaf(hv.z, w[0][k4 * 4 + 2], fmaf(hv.w, w[0][k4 * 4 + 3], p0))));
      p1 = fmaf(hv.x, w[1][k4 * 4], fmaf(hv.y, w[1][k4 * 4 + 1], fmaf(hv.z, w[1][k4 * 4 + 2], fmaf(hv.w, w[1][k4 * 4 + 3], p1))));
      p2 = fmaf(hv.x, w[2][k4 * 4], fmaf(hv.y, w[2][k4 * 4 + 1], fmaf(hv.z, w[2][k4 * 4 + 2], fmaf(hv.w, w[2][k4 * 4 + 3], p2))));
      p3 = fmaf(hv.x, w[3][k4 * 4], fmaf(hv.y, w[3][k4 * 4 + 1], fmaf(hv.z, w[3][k4 * 4 + 2], fmaf(hv.w, w[3][k4 * 4 + 3], p3))));
    }
    ps[(ks * 4 + 0) * 128 + jj] = p0;
    ps[(ks * 4 + 1) * 128 + jj] = p1;
    ps[(ks * 4 + 2) * 128 + jj] = p2;
    ps[(ks * 4 + 3) * 128 + jj] = p3;
    barrier_lgkm();
    {
      float gsum = xcur + ((ps[(0 * 4 + ks) * 128 + jj] + ps[(1 * 4 + ks) * 128 + jj]) +
                           (ps[(2 * 4 + ks) * 128 + jj] + ps[(3 * 4 + ks) * 128 + jj]));
      gs[tid] = (ks == 2) ? tanhf(gsum) : sigmoidf_(gsum);
    }
    barrier_lgkm();
    if (tid < H_) {
      float ig = gs[jj];
      float fg = gs[128 + jj];
      float gt = gs[256 + jj];
      float og = gs[384 + jj];
      c = fg * c + ig * gt;
      float hn = og * tanhf(c);
      h0s[jj] = hn;
      hs1[((size_t)(b * T_ + t)) * H_ + jj] = hn;
    }
    barrier_lgkm();
    xcur = xnxt;
  }
}

// ---------------------------------------------------------------------------
// Kernel 4: xg1 = hs1 @ wih1^T. (unchanged)
// ---------------------------------------------------------------------------
__global__ __launch_bounds__(512) void k_xg1(
    const float* __restrict__ hs1, const float* __restrict__ wih1T,
    float* __restrict__ xg1) {
  __shared__ __align__(16) float hsS[8][128];
  const int r0 = blockIdx.x * 8;
  const int tid = threadIdx.x;
  for (int i = tid; i < 8 * 128; i += 512) ((float*)hsS)[i] = hs1[(size_t)r0 * 128 + i];
  __syncthreads();
  float acc[8] = {0.f, 0.f, 0.f, 0.f, 0.f, 0.f, 0.f, 0.f};
#pragma unroll 4
  for (int k4 = 0; k4 < 32; ++k4) {
    float w0 = wih1T[(4 * k4 + 0) * 512 + tid];
    float w1v = wih1T[(4 * k4 + 1) * 512 + tid];
    float w2v = wih1T[(4 * k4 + 2) * 512 + tid];
    float w3v = wih1T[(4 * k4 + 3) * 512 + tid];
#pragma unroll
    for (int i = 0; i < 8; ++i) {
      float4 h = *(const float4*)(&hsS[i][4 * k4]);
      acc[i] += h.x * w0 + h.y * w1v + h.z * w2v + h.w * w3v;
    }
  }
#pragma unroll
  for (int i = 0; i < 8; ++i) xg1[((size_t)(r0 + i)) * 512 + tid] = acc[i];
}

// ---------------------------------------------------------------------------
// Kernel 5: LSTM layer 1 + FC tail. (unchanged from round 13)
// ---------------------------------------------------------------------------
__global__ __launch_bounds__(512) void k_lstm1(
    const float* __restrict__ xg1, const float* __restrict__ whh1T,
    const float* __restrict__ fc1, const float* __restrict__ fc2,
    const int* __restrict__ lengths, float* __restrict__ out) {
  __shared__ __align__(16) float h1s[H_];
  __shared__ float ps[16 * 128];
  __shared__ float gs[512];
  __shared__ float tmp10[10];
  const int b = blockIdx.x;
  const int tid = threadIdx.x;
  const int ks = tid >> 7;
  const int jj = tid & 127;
  float w[4][32];
#pragma unroll
  for (int kk = 0; kk < 32; ++kk) {
#pragma unroll
    for (int q = 0; q < 4; ++q)
      w[q][kk] = whh1T[(ks * 32 + kk) * 512 + q * 128 + jj];
  }
  if (tid < H_) h1s[tid] = 0.f;
  float c = 0.f;
  const int len = lengths[b];
  float xcur = xg1[(size_t)(b * T_) * 512 + tid];
  barrier_lgkm();
  for (int t = 0; t < len; ++t) {
    float xnxt = (t + 1 < len) ? xg1[(size_t)(b * T_ + t + 1) * 512 + tid] : 0.f;
    float p0 = 0.f, p1 = 0.f, p2 = 0.f, p3 = 0.f;
#pragma unroll
    for (int k4 = 0; k4 < 8; ++k4) {
      float4 hv = *(const float4*)(h1s + ks * 32 + k4 * 4);
      p0 = fmaf(hv.x, w[0][k4 * 4], fmaf(hv.y, w[0][k4 * 4 + 1], fmaf(hv.z, w[0][k4 * 4 + 2], fmaf(hv.w, w[0][k4 * 4 + 3], p0))));
      p1 = fmaf(hv.x, w[1][k4 * 4], fmaf(hv.y, w[1][k4 * 4 + 1], fmaf(hv.z, w[1][k4 * 4 + 2], fmaf(hv.w, w[1][k4 * 4 + 3], p1))));
      p2 = fmaf(hv.x, w[2][k4 * 4], fmaf(hv.y, w[2][k4 * 4 + 1], fmaf(hv.z, w[2][k4 * 4 + 2], fmaf(hv.w, w[2][k4 * 4 + 3], p2))));
      p3 = fmaf(hv.x, w[3][k4 * 4], fmaf(hv.y, w[3][k4 * 4 + 1], fmaf(hv.z, w[3][k4 * 4 + 2], fmaf(hv.w, w[3][k4 * 4 + 3], p3))));
    }
    ps[(ks * 4 + 0) * 128 + jj] = p0;
    ps[(ks * 4 + 1) * 128 + jj] = p1;
    ps[(ks * 4 + 2) * 128 + jj] = p2;
    ps[(ks * 4 + 3) * 128 + jj] = p3;
    barrier_lgkm();
    {
      float gsum = xcur + ((ps[(0 * 4 + ks) * 128 + jj] + ps[(1 * 4 + ks) * 128 + jj]) +
                           (ps[(2 * 4 + ks) * 128 + jj] + ps[(3 * 4 + ks) * 128 + jj]));
      gs[tid] = (ks == 2) ? tanhf(gsum) : sigmoidf_(gsum);
    }
    barrier_lgkm();
    if (tid < H_) {
      float ig = gs[jj];
      float fg = gs[128 + jj];
      float gt = gs[256 + jj];
      float og = gs[384 + jj];
      c = fg * c + ig * gt;
      float hn = og * tanhf(c);
      h1s[jj] = hn;
    }
    barrier_lgkm();
    xcur = xnxt;
  }
  if (tid < 10) {
    const float* fr = fc1 + tid * H_;
    float s = 0.f;
#pragma unroll 4
    for (int k = 0; k < H_; ++k) s += h1s[k] * fr[k];
    tmp10[tid] = leakyf(s);
  }
  barrier_lgkm();
  if (tid < 2) {
    const float* fr = fc2 + tid * 10;
    float s = 0.f;
#pragma unroll
    for (int j = 0; j < 10; ++j) s += tmp10[j] * fr[j];
    out[b * 2 + tid] = leakyf(s);
  }
}

extern "C" void kernel_launch(void* const* d_in, const int* in_sizes, int n_in,
                              void* d_out, int out_size, void* d_ws, size_t ws_size,
                              hipStream_t stream) {
  const float* X = (const float*)d_in[0];
  const int* lengths = (const int*)d_in[1];
  const float* w1 = (const float*)d_in[2];
  const float* w2 = (const float*)d_in[3];
  const float* w3 = (const float*)d_in[4];
  const float* linw = (const float*)d_in[5];
  const float* wih0 = (const float*)d_in[6];
  const float* whh0 = (const float*)d_in[7];
  const float* wih1 = (const float*)d_in[8];
  const float* whh1 = (const float*)d_in[9];
  const float* fc1 = (const float*)d_in[10];
  const float* fc2 = (const float*)d_in[11];

  char* wsb = (char*)d_ws;
  size_t off = 0;
  auto alloc = [&](size_t bytes) {
    char* p = wsb + off;
    off += (bytes + 511) & ~(size_t)511;
    return p;
  };
  unsigned short* s3g = (unsigned short*)alloc(2048 * 1728 * 2);
  float* xg0 = (float*)alloc(2048 * 512 * 4);
  unsigned short* w1eh = (unsigned short*)alloc(1024 * 2);
  unsigned short* w1el = (unsigned short*)alloc(1024 * 2);
  unsigned short* w2h = (unsigned short*)alloc(20480 * 2);
  unsigned short* w2l = (unsigned short*)alloc(20480 * 2);
  unsigned short* w3h = (unsigned short*)alloc(5120 * 2);
  unsigned short* w3l = (unsigned short*)alloc(5120 * 2);
  unsigned short* linwh = (unsigned short*)alloc(172800 * 2);
  unsigned short* linwl = (unsigned short*)alloc(172800 * 2);
  unsigned short* wih0h = (unsigned short*)alloc(65536 * 2);
  unsigned short* wih0l = (unsigned short*)alloc(65536 * 2);
  float* whh0T = (float*)alloc(65536 * 4);
  float* wih1T = (float*)alloc(65536 * 4);
  float* whh1T = (float*)alloc(65536 * 4);
  float* hs1 = (float*)alloc(262144 * 4);
  float* xg1 = (float*)alloc(2048 * 512 * 4);

  k_prep<<<1803, 256, 0, stream>>>(w1, w2, w3, linw, wih0, whh0, wih1, whh1,
                                   w1eh, w1el, w2h, w2l, w3h, w3l,
                                   linwh, linwl, wih0h, wih0l,
                                   whh0T, wih1T, whh1T);
  k_conv123<<<2048, 512, 0, stream>>>(X, w1, w2h, w2l, w3h, w3l, s3g);
  k_gemm_fx<<<128, 448, 0, stream>>>(s3g, linwh, linwl, wih0h, wih0l, xg0);
  k_lstm0<<<32, 512, 0, stream>>>(xg0, whh0T, lengths, hs1);
  k_xg1<<<256, 512, 0, stream>>>(hs1, wih1T, xg1);
  k_lstm1<<<32, 512, 0, stream>>>(xg1, whh1T, fc1, fc2, lengths, (float*)d_out);
}

// Round 15
// 254.790 us; speedup vs baseline: 1.0714x; 1.0714x over previous
//
#include <hip/hip_runtime.h>
#include <hip/hip_bf16.h>

#define B_ 32
#define T_ 64
#define H_ 128
#define L3OUT 54
#define FLAT_ 1728

typedef __attribute__((ext_vector_type(8))) short bf16x8;
typedef __attribute__((ext_vector_type(4))) float f32x4;

__device__ __forceinline__ float leakyf(float v) { return v > 0.f ? v : 0.01f * v; }
__device__ __forceinline__ float sigmoidf_(float v) { return 1.f / (1.f + expf(-v)); }
__device__ __forceinline__ unsigned int bf16rne(float v) {
  unsigned int b = __float_as_uint(v);
  return (b + 0x7FFFu + ((b >> 16) & 1u)) >> 16;
}
__device__ __forceinline__ unsigned int pk2bf(float lo, float hi) {
  __hip_bfloat162 h2 = __float22bfloat162_rn(make_float2(lo, hi));  // v_cvt_pk_bf16_f32, RNE
  return *reinterpret_cast<unsigned int*>(&h2);
}
__device__ __forceinline__ bf16x8 ldb8(const unsigned short* p) {
  return *(const bf16x8*)p;
}
// LDS-only barrier (all cross-thread deps in users are LDS).
__device__ __forceinline__ void barrier_lgkm() {
  asm volatile("s_waitcnt lgkmcnt(0)\n\ts_barrier" ::: "memory");
}

// ---------------------------------------------------------------------------
// Kernel 0: weight prep + transposes. NEW range: wih1 -> bf16 hi/lo
// [512][128] row-major (for the fused-LSTM xg1 MFMA). 2059 blocks.
// ---------------------------------------------------------------------------
__global__ __launch_bounds__(256) void k_prep(
    const float* __restrict__ w1, const float* __restrict__ w2,
    const float* __restrict__ w3, const float* __restrict__ linw,
    const float* __restrict__ wih0, const float* __restrict__ whh0,
    const float* __restrict__ wih1, const float* __restrict__ whh1,
    unsigned short* __restrict__ w1eh, unsigned short* __restrict__ w1el,
    unsigned short* __restrict__ w2h, unsigned short* __restrict__ w2l,
    unsigned short* __restrict__ w3h, unsigned short* __restrict__ w3l,
    unsigned short* __restrict__ linwh, unsigned short* __restrict__ linwl,
    unsigned short* __restrict__ wih0h, unsigned short* __restrict__ wih0l,
    unsigned short* __restrict__ wih1h, unsigned short* __restrict__ wih1l,
    float* __restrict__ whh0T, float* __restrict__ wih1T,
    float* __restrict__ whh1T) {
  const int e = blockIdx.x * 256 + threadIdx.x;
  if (e >= 264960 && e < 461568) {
    int e5 = e - 264960;
    int m = e5 >> 16, r = e5 & 65535;
    int k = r >> 9, j = r & 511;
    const float* src = (m == 0) ? whh0 : ((m == 1) ? wih1 : whh1);
    float* dst = (m == 0) ? whh0T : ((m == 1) ? wih1T : whh1T);
    dst[r] = src[j * 128 + k];
    return;
  }
  float v;
  unsigned short* dh;
  unsigned short* dl;
  int di;
  if (e < 20480) {
    int cc = e / 5120, rem = e - cc * 5120;
    int c2 = rem / 160, r = rem - c2 * 160;
    int tap = r >> 5, c1l = r & 31;
    v = w2[c2 * 640 + (cc * 32 + c1l) * 5 + tap];
    dh = w2h; dl = w2l; di = e;
  } else if (e < 25600) {
    int e2 = e - 20480;
    int c3 = e2 / 160, r = e2 - c3 * 160;
    int tap = r >> 5, c2 = r & 31;
    v = w3[c3 * 160 + c2 * 5 + tap];
    dh = w3h; dl = w3l; di = e2;
  } else if (e < 198400) {
    int e3 = e - 25600;
    v = linw[e3];
    dh = linwh; dl = linwl; di = e3;
  } else if (e < 263936) {
    int e4 = e - 198400;
    int g = e4 >> 7, k = e4 & 127;
    v = (k < 100) ? wih0[g * 100 + k] : 0.f;
    dh = wih0h; dl = wih0l; di = e4;
  } else if (e < 264960) {
    int i = e - 263936;
    int c1 = i >> 3, j = i & 7;
    v = (j < 5) ? w1[c1 * 5 + j] : 0.f;
    dh = w1eh; dl = w1el; di = i;
  } else {  // e in [461568, 527104): wih1 bf16 split
    int e6 = e - 461568;
    v = wih1[e6];
    dh = wih1h; dl = wih1l; di = e6;
  }
  unsigned int hb = bf16rne(v);
  float hf = __uint_as_float(hb << 16);
  unsigned int lb = bf16rne(v - hf);
  dh[di] = (unsigned short)hb;
  dl[di] = (unsigned short)lb;
}

// ---------------------------------------------------------------------------
// Kernel 1: conv1 (fp32) + conv2 (MFMA) + conv3 (MFMA). Round-13 version
// (round-14 prefetch pipeline reverted: measured regression 110->116).
// ---------------------------------------------------------------------------
__global__ __launch_bounds__(512) void k_conv123(
    const float* __restrict__ X, const float* __restrict__ w1,
    const unsigned short* __restrict__ w2h, const unsigned short* __restrict__ w2l,
    const unsigned short* __restrict__ w3h, const unsigned short* __restrict__ w3l,
    unsigned short* __restrict__ s3g) {
  __shared__ __align__(16) float Xs[1504];
  __shared__ __align__(16) unsigned int AhU[10640];  // [532 rows][20 u32]

  const int n = blockIdx.x;
  const int tid = threadIdx.x;
  const int lane = tid & 63;
  const int w = tid >> 6;        // 0..7
  const int l15 = lane & 15;
  const int cg = lane >> 4;

  const float* Xn = X + (size_t)n * 1500;
  for (int i = tid; i < 1500; i += 512) Xs[i] = Xn[i];
  if (tid < 4) Xs[1500 + tid] = 0.f;
  for (int i = tid; i < 640; i += 512) AhU[10000 + i] = 0u;  // rows 500..531
  barrier_lgkm();

  float x0 = 0.f, x1 = 0.f, x2 = 0.f, x3 = 0.f, x4 = 0.f;
  if (tid < 500) {
    const float* xp = Xs + 3 * tid;
    x0 = xp[0]; x1 = xp[1]; x2 = xp[2]; x3 = xp[3]; x4 = xp[4];
  }

  f32x4 acc2[2][2];
#pragma unroll
  for (int a = 0; a < 2; ++a)
#pragma unroll
    for (int m = 0; m < 2; ++m) acc2[a][m] = (f32x4){0.f, 0.f, 0.f, 0.f};

  for (int cc = 0; cc < 4; ++cc) {
    barrier_lgkm();
    if (tid < 500) {
      const float* wc = w1 + cc * 160;
      unsigned int rowbuf[16];
#pragma unroll
      for (int p = 0; p < 16; ++p) {
        const float* wa = wc + 10 * p;
        float vA = fmaf(x4, wa[4], fmaf(x3, wa[3], fmaf(x2, wa[2], fmaf(x1, wa[1], x0 * wa[0]))));
        float vB = fmaf(x4, wa[9], fmaf(x3, wa[8], fmaf(x2, wa[7], fmaf(x1, wa[6], x0 * wa[5]))));
        vA = fmaxf(vA, 0.01f * vA);
        vB = fmaxf(vB, 0.01f * vB);
        rowbuf[p] = pk2bf(vA, vB);
      }
#pragma unroll
      for (int q = 0; q < 4; ++q)
        *(uint4*)(&AhU[tid * 20 + 4 * q]) = *(uint4*)(&rowbuf[4 * q]);
    }
    barrier_lgkm();
    const unsigned short* w2hB = w2h + cc * 5120;
    const unsigned short* w2lB = w2l + cc * 5120;
#pragma unroll
    for (int tap = 0; tap < 5; ++tap) {
      const int wc = tap * 32 + cg * 8;
      bf16x8 ah0 = ldb8(w2hB + l15 * 160 + wc);
      bf16x8 ah1 = ldb8(w2hB + (l15 + 16) * 160 + wc);
      bf16x8 al0 = ldb8(w2lB + l15 * 160 + wc);
      bf16x8 al1 = ldb8(w2lB + (l15 + 16) * 160 + wc);
      {
        bf16x8 bfr = ldb8((const unsigned short*)AhU + (3 * (w * 16 + l15) + tap) * 40 + cg * 8);
        acc2[0][0] = __builtin_amdgcn_mfma_f32_16x16x32_bf16(ah0, bfr, acc2[0][0], 0, 0, 0);
        acc2[0][0] = __builtin_amdgcn_mfma_f32_16x16x32_bf16(al0, bfr, acc2[0][0], 0, 0, 0);
        acc2[0][1] = __builtin_amdgcn_mfma_f32_16x16x32_bf16(ah1, bfr, acc2[0][1], 0, 0, 0);
        acc2[0][1] = __builtin_amdgcn_mfma_f32_16x16x32_bf16(al1, bfr, acc2[0][1], 0, 0, 0);
      }
      if (w < 3) {
        int nt = 8 + w;
        bf16x8 bfr = ldb8((const unsigned short*)AhU + (3 * (nt * 16 + l15) + tap) * 40 + cg * 8);
        acc2[1][0] = __builtin_amdgcn_mfma_f32_16x16x32_bf16(ah0, bfr, acc2[1][0], 0, 0, 0);
        acc2[1][0] = __builtin_amdgcn_mfma_f32_16x16x32_bf16(al0, bfr, acc2[1][0], 0, 0, 0);
        acc2[1][1] = __builtin_amdgcn_mfma_f32_16x16x32_bf16(ah1, bfr, acc2[1][1], 0, 0, 0);
        acc2[1][1] = __builtin_amdgcn_mfma_f32_16x16x32_bf16(al1, bfr, acc2[1][1], 0, 0, 0);
      }
    }
  }
  barrier_lgkm();
  for (int i = tid; i < 400; i += 512) AhU[176 * 20 + i] = 0u;
#pragma unroll
  for (int nti = 0; nti < 2; ++nti) {
    int nt = (nti == 0) ? w : (8 + w);
    if (nti == 0 || w < 3) {
      int l2 = nt * 16 + l15;
#pragma unroll
      for (int mt = 0; mt < 2; ++mt) {
#pragma unroll
        for (int j = 0; j < 2; ++j) {
          float e0 = leakyf(acc2[nti][mt][2 * j]);
          float e1 = leakyf(acc2[nti][mt][2 * j + 1]);
          AhU[l2 * 20 + mt * 8 + cg * 2 + j] = pk2bf(e0, e1);
        }
      }
    }
  }
  barrier_lgkm();
  if (w < 4) {
    f32x4 a3[2];
    a3[0] = (f32x4){0.f, 0.f, 0.f, 0.f};
    a3[1] = (f32x4){0.f, 0.f, 0.f, 0.f};
#pragma unroll
    for (int tap = 0; tap < 5; ++tap) {
      const int wc = tap * 32 + cg * 8;
      bf16x8 wh0 = ldb8(w3h + l15 * 160 + wc);
      bf16x8 wh1 = ldb8(w3h + (l15 + 16) * 160 + wc);
      bf16x8 wl0 = ldb8(w3l + l15 * 160 + wc);
      bf16x8 wl1 = ldb8(w3l + (l15 + 16) * 160 + wc);
      bf16x8 bfr = ldb8((const unsigned short*)AhU + (3 * (w * 16 + l15) + tap) * 40 + cg * 8);
      a3[0] = __builtin_amdgcn_mfma_f32_16x16x32_bf16(wh0, bfr, a3[0], 0, 0, 0);
      a3[0] = __builtin_amdgcn_mfma_f32_16x16x32_bf16(wl0, bfr, a3[0], 0, 0, 0);
      a3[1] = __builtin_amdgcn_mfma_f32_16x16x32_bf16(wh1, bfr, a3[1], 0, 0, 0);
      a3[1] = __builtin_amdgcn_mfma_f32_16x16x32_bf16(wl1, bfr, a3[1], 0, 0, 0);
    }
    int l3 = w * 16 + l15;
    if (l3 < L3OUT) {
#pragma unroll
      for (int mt = 0; mt < 2; ++mt) {
#pragma unroll
        for (int r = 0; r < 4; ++r) {
          int c3 = mt * 16 + cg * 4 + r;
          s3g[(size_t)n * FLAT_ + c3 * L3OUT + l3] = (unsigned short)bf16rne(leakyf(a3[mt][r]));
        }
      }
    }
  }
}

// ---------------------------------------------------------------------------
// Kernel 2: FUSED fe + xg0. (unchanged)
// ---------------------------------------------------------------------------
__global__ __launch_bounds__(448) void k_gemm_fx(
    const unsigned short* __restrict__ s3g,
    const unsigned short* __restrict__ linwh, const unsigned short* __restrict__ linwl,
    const unsigned short* __restrict__ wih0h, const unsigned short* __restrict__ wih0l,
    float* __restrict__ xg0) {
  __shared__ __align__(16) unsigned short fehS[16][136];
  __shared__ __align__(16) unsigned short felS[16][136];

  const int m0 = blockIdx.x * 16;
  const int tid = threadIdx.x;
  const int lane = tid & 63;
  const int w = tid >> 6;
  const int l15 = lane & 15;
  const int cg = lane >> 4;

  if (tid < 192) {
    int r = tid / 12, c = tid - r * 12;
    ((unsigned int*)&fehS[r][112])[c] = 0u;
    ((unsigned int*)&felS[r][112])[c] = 0u;
  }

  int brow = w * 16 + l15;
  if (brow > 99) brow = 99;
  const unsigned short* ap = s3g + (size_t)(m0 + l15) * FLAT_ + cg * 8;
  const unsigned short* bhp = linwh + (size_t)brow * FLAT_ + cg * 8;
  const unsigned short* blp = linwl + (size_t)brow * FLAT_ + cg * 8;

  f32x4 acc = (f32x4){0.f, 0.f, 0.f, 0.f};
#pragma unroll 6
  for (int ks = 0; ks < 54; ++ks) {
    bf16x8 af = ldb8(ap + ks * 32);
    bf16x8 bh = ldb8(bhp + ks * 32);
    bf16x8 bl = ldb8(blp + ks * 32);
    acc = __builtin_amdgcn_mfma_f32_16x16x32_bf16(af, bh, acc, 0, 0, 0);
    acc = __builtin_amdgcn_mfma_f32_16x16x32_bf16(af, bl, acc, 0, 0, 0);
  }
  const int jcol = w * 16 + l15;
#pragma unroll
  for (int r = 0; r < 4; ++r) {
    float v = acc[r];
    unsigned int hb = bf16rne(v);
    float hf = __uint_as_float(hb << 16);
    unsigned int lb = bf16rne(v - hf);
    fehS[cg * 4 + r][jcol] = (unsigned short)hb;
    felS[cg * 4 + r][jcol] = (unsigned short)lb;
  }
  __syncthreads();

#pragma unroll
  for (int nt0 = 0; nt0 < 5; ++nt0) {
    int nt = w + 7 * nt0;
    if (nt < 32) {
      f32x4 a = (f32x4){0.f, 0.f, 0.f, 0.f};
#pragma unroll
      for (int ks = 0; ks < 4; ++ks) {
        bf16x8 ah = ldb8(&fehS[l15][ks * 32 + cg * 8]);
        bf16x8 al = ldb8(&felS[l15][ks * 32 + cg * 8]);
        int br = nt * 16 + l15;
        bf16x8 bh = ldb8(wih0h + (size_t)br * 128 + ks * 32 + cg * 8);
        bf16x8 bl = ldb8(wih0l + (size_t)br * 128 + ks * 32 + cg * 8);
        a = __builtin_amdgcn_mfma_f32_16x16x32_bf16(ah, bh, a, 0, 0, 0);
        a = __builtin_amdgcn_mfma_f32_16x16x32_bf16(ah, bl, a, 0, 0, 0);
        a = __builtin_amdgcn_mfma_f32_16x16x32_bf16(al, bh, a, 0, 0, 0);
      }
#pragma unroll
      for (int r = 0; r < 4; ++r)
        xg0[(size_t)(m0 + cg * 4 + r) * 512 + nt * 16 + l15] = a[r];
    }
  }
}

// ---------------------------------------------------------------------------
// Kernel 3: FUSED two-layer LSTM with producer/consumer chunk pipeline.
// 64 blocks x 512 thr; all co-resident (64 <= 256 CUs) => spin-wait safe.
// Blocks 0..31 (producer, batch b): layer-0 steps (3-phase, as before);
//   h(t) also packed bf16 hi/lo into LDS chunk history. Every 16 steps:
//   xg1 chunk = wih1 @ h_chunk via 3-pass MFMA -> global, __syncthreads
//   (drains vmcnt), then tid0 release-stores flags[b] (agent scope =>
//   L2 writeback; consumer acquire => cross-XCD invalidate).
// Blocks 32..63 (consumer, batch b-32): layer-1 steps; waits on flags[b]
//   only at chunk boundaries; FC tail at end.
// ---------------------------------------------------------------------------
__global__ __launch_bounds__(512) void k_lstm_fused(
    const float* __restrict__ xg0, const float* __restrict__ whh0T,
    const float* __restrict__ whh1T,
    const unsigned short* __restrict__ wih1h, const unsigned short* __restrict__ wih1l,
    const float* __restrict__ fc1, const float* __restrict__ fc2,
    const int* __restrict__ lengths, float* __restrict__ xg1,
    int* __restrict__ flags, float* __restrict__ out) {
  __shared__ __align__(16) float hs[H_];
  __shared__ float ps[16 * 128];
  __shared__ float gs[512];
  __shared__ __align__(16) unsigned short hBh[16][136];
  __shared__ __align__(16) unsigned short hBl[16][136];
  __shared__ float tmp10[10];

  const int bid = blockIdx.x;
  const int tid = threadIdx.x;
  const int lane = tid & 63;
  const int wv = tid >> 6;
  const int l15 = lane & 15;
  const int cg = lane >> 4;
  const int ks = tid >> 7;
  const int jj = tid & 127;

  if (bid < 32) {
    // ================= PRODUCER: layer 0, batch b =================
    const int b = bid;
    float w[4][32];
#pragma unroll
    for (int kk = 0; kk < 32; ++kk) {
#pragma unroll
      for (int q = 0; q < 4; ++q)
        w[q][kk] = whh0T[(ks * 32 + kk) * 512 + q * 128 + jj];
    }
    if (tid < H_) hs[tid] = 0.f;
    float c = 0.f;
    const int len = lengths[b];
    float xcur = xg0[(size_t)(b * T_) * 512 + tid];
    barrier_lgkm();
    for (int ck = 0; ck < 4; ++ck) {
      const int t0 = ck * 16;
      if (t0 >= len) break;
      for (int ts = 0; ts < 16; ++ts) {
        const int t = t0 + ts;
        if (t >= len) break;
        float xnxt = (t + 1 < len) ? xg0[(size_t)(b * T_ + t + 1) * 512 + tid] : 0.f;
        float p0 = 0.f, p1 = 0.f, p2 = 0.f, p3 = 0.f;
#pragma unroll
        for (int k4 = 0; k4 < 8; ++k4) {
          float4 hv = *(const float4*)(hs + ks * 32 + k4 * 4);
          p0 = fmaf(hv.x, w[0][k4 * 4], fmaf(hv.y, w[0][k4 * 4 + 1], fmaf(hv.z, w[0][k4 * 4 + 2], fmaf(hv.w, w[0][k4 * 4 + 3], p0))));
          p1 = fmaf(hv.x, w[1][k4 * 4], fmaf(hv.y, w[1][k4 * 4 + 1], fmaf(hv.z, w[1][k4 * 4 + 2], fmaf(hv.w, w[1][k4 * 4 + 3], p1))));
          p2 = fmaf(hv.x, w[2][k4 * 4], fmaf(hv.y, w[2][k4 * 4 + 1], fmaf(hv.z, w[2][k4 * 4 + 2], fmaf(hv.w, w[2][k4 * 4 + 3], p2))));
          p3 = fmaf(hv.x, w[3][k4 * 4], fmaf(hv.y, w[3][k4 * 4 + 1], fmaf(hv.z, w[3][k4 * 4 + 2], fmaf(hv.w, w[3][k4 * 4 + 3], p3))));
        }
        ps[(ks * 4 + 0) * 128 + jj] = p0;
        ps[(ks * 4 + 1) * 128 + jj] = p1;
        ps[(ks * 4 + 2) * 128 + jj] = p2;
        ps[(ks * 4 + 3) * 128 + jj] = p3;
        barrier_lgkm();
        {
          float gsum = xcur + ((ps[(0 * 4 + ks) * 128 + jj] + ps[(1 * 4 + ks) * 128 + jj]) +
                               (ps[(2 * 4 + ks) * 128 + jj] + ps[(3 * 4 + ks) * 128 + jj]));
          gs[tid] = (ks == 2) ? tanhf(gsum) : sigmoidf_(gsum);
        }
        barrier_lgkm();
        if (tid < H_) {
          float ig = gs[jj];
          float fg = gs[128 + jj];
          float gt = gs[256 + jj];
          float og = gs[384 + jj];
          c = fg * c + ig * gt;
          float hn = og * tanhf(c);
          hs[jj] = hn;
          unsigned int hb = bf16rne(hn);
          hBh[ts][jj] = (unsigned short)hb;
          float hf = __uint_as_float(hb << 16);
          hBl[ts][jj] = (unsigned short)bf16rne(hn - hf);
        }
        barrier_lgkm();
        xcur = xnxt;
      }
      // xg1 chunk = wih1 @ h_chunk (3-pass bf16 MFMA). Cols t>=len unread.
#pragma unroll
      for (int mt4 = 0; mt4 < 4; ++mt4) {
        const int mt = wv * 4 + mt4;
        f32x4 a = (f32x4){0.f, 0.f, 0.f, 0.f};
#pragma unroll
        for (int kst = 0; kst < 4; ++kst) {
          bf16x8 bh = ldb8(&hBh[l15][kst * 32 + cg * 8]);
          bf16x8 bl = ldb8(&hBl[l15][kst * 32 + cg * 8]);
          const int ar = mt * 16 + l15;
          bf16x8 awh = ldb8(wih1h + (size_t)ar * 128 + kst * 32 + cg * 8);
          bf16x8 awl = ldb8(wih1l + (size_t)ar * 128 + kst * 32 + cg * 8);
          a = __builtin_amdgcn_mfma_f32_16x16x32_bf16(awh, bh, a, 0, 0, 0);
          a = __builtin_amdgcn_mfma_f32_16x16x32_bf16(awl, bh, a, 0, 0, 0);
          a = __builtin_amdgcn_mfma_f32_16x16x32_bf16(awh, bl, a, 0, 0, 0);
        }
        // C/D: col=l15 (t within chunk), row=cg*4+r (j within m-tile)
        *(float4*)&xg1[(size_t)(b * T_ + t0 + l15) * 512 + mt * 16 + cg * 4] =
            *(float4*)&a;
      }
      __syncthreads();  // drain vmcnt: all waves' xg1 stores complete
      if (tid == 0)
        __hip_atomic_store(flags + b, ck + 1, __ATOMIC_RELEASE, __HIP_MEMORY_SCOPE_AGENT);
    }
  } else {
    // ================= CONSUMER: layer 1, batch b =================
    const int b = bid - 32;
    float w[4][32];
#pragma unroll
    for (int kk = 0; kk < 32; ++kk) {
#pragma unroll
      for (int q = 0; q < 4; ++q)
        w[q][kk] = whh1T[(ks * 32 + kk) * 512 + q * 128 + jj];
    }
    if (tid < H_) hs[tid] = 0.f;
    float c = 0.f;
    const int len = lengths[b];
    const float* xg1r = xg1 + (size_t)b * T_ * 512;
    float xcur = 0.f;
    barrier_lgkm();
    for (int t = 0; t < len; ++t) {
      if ((t & 15) == 0) {
        const int ck = t >> 4;
        if (tid == 0) {
          while (__hip_atomic_load(flags + b, __ATOMIC_ACQUIRE, __HIP_MEMORY_SCOPE_AGENT) <= ck)
            __builtin_amdgcn_s_sleep(2);
        }
        __syncthreads();
        xcur = xg1r[(size_t)t * 512 + tid];
      }
      float xnxt = ((((t + 1) & 15) != 0) && (t + 1 < len))
                       ? xg1r[(size_t)(t + 1) * 512 + tid] : 0.f;
      float p0 = 0.f, p1 = 0.f, p2 = 0.f, p3 = 0.f;
#pragma unroll
      for (int k4 = 0; k4 < 8; ++k4) {
        float4 hv = *(const float4*)(hs + ks * 32 + k4 * 4);
        p0 = fmaf(hv.x, w[0][k4 * 4], fmaf(hv.y, w[0][k4 * 4 + 1], fmaf(hv.z, w[0][k4 * 4 + 2], fmaf(hv.w, w[0][k4 * 4 + 3], p0))));
        p1 = fmaf(hv.x, w[1][k4 * 4], fmaf(hv.y, w[1][k4 * 4 + 1], fmaf(hv.z, w[1][k4 * 4 + 2], fmaf(hv.w, w[1][k4 * 4 + 3], p1))));
        p2 = fmaf(hv.x, w[2][k4 * 4], fmaf(hv.y, w[2][k4 * 4 + 1], fmaf(hv.z, w[2][k4 * 4 + 2], fmaf(hv.w, w[2][k4 * 4 + 3], p2))));
        p3 = fmaf(hv.x, w[3][k4 * 4], fmaf(hv.y, w[3][k4 * 4 + 1], fmaf(hv.z, w[3][k4 * 4 + 2], fmaf(hv.w, w[3][k4 * 4 + 3], p3))));
      }
      ps[(ks * 4 + 0) * 128 + jj] = p0;
      ps[(ks * 4 + 1) * 128 + jj] = p1;
      ps[(ks * 4 + 2) * 128 + jj] = p2;
      ps[(ks * 4 + 3) * 128 + jj] = p3;
      barrier_lgkm();
      {
        float gsum = xcur + ((ps[(0 * 4 + ks) * 128 + jj] + ps[(1 * 4 + ks) * 128 + jj]) +
                             (ps[(2 * 4 + ks) * 128 + jj] + ps[(3 * 4 + ks) * 128 + jj]));
        gs[tid] = (ks == 2) ? tanhf(gsum) : sigmoidf_(gsum);
      }
      barrier_lgkm();
      if (tid < H_) {
        float ig = gs[jj];
        float fg = gs[128 + jj];
        float gt = gs[256 + jj];
        float og = gs[384 + jj];
        c = fg * c + ig * gt;
        float hn = og * tanhf(c);
        hs[jj] = hn;
      }
      barrier_lgkm();
      xcur = xnxt;
    }
    if (tid < 10) {
      const float* fr = fc1 + tid * H_;
      float s = 0.f;
#pragma unroll 4
      for (int k = 0; k < H_; ++k) s += hs[k] * fr[k];
      tmp10[tid] = leakyf(s);
    }
    barrier_lgkm();
    if (tid < 2) {
      const float* fr = fc2 + tid * 10;
      float s = 0.f;
#pragma unroll
      for (int j = 0; j < 10; ++j) s += tmp10[j] * fr[j];
      out[b * 2 + tid] = leakyf(s);
    }
  }
}

extern "C" void kernel_launch(void* const* d_in, const int* in_sizes, int n_in,
                              void* d_out, int out_size, void* d_ws, size_t ws_size,
                              hipStream_t stream) {
  const float* X = (const float*)d_in[0];
  const int* lengths = (const int*)d_in[1];
  const float* w1 = (const float*)d_in[2];
  const float* w2 = (const float*)d_in[3];
  const float* w3 = (const float*)d_in[4];
  const float* linw = (const float*)d_in[5];
  const float* wih0 = (const float*)d_in[6];
  const float* whh0 = (const float*)d_in[7];
  const float* wih1 = (const float*)d_in[8];
  const float* whh1 = (const float*)d_in[9];
  const float* fc1 = (const float*)d_in[10];
  const float* fc2 = (const float*)d_in[11];

  char* wsb = (char*)d_ws;
  size_t off = 0;
  auto alloc = [&](size_t bytes) {
    char* p = wsb + off;
    off += (bytes + 511) & ~(size_t)511;
    return p;
  };
  unsigned short* s3g = (unsigned short*)alloc(2048 * 1728 * 2);
  float* xg0 = (float*)alloc(2048 * 512 * 4);
  float* xg1 = (float*)alloc(2048 * 512 * 4);
  int* flags = (int*)alloc(32 * 4);
  unsigned short* w1eh = (unsigned short*)alloc(1024 * 2);
  unsigned short* w1el = (unsigned short*)alloc(1024 * 2);
  unsigned short* w2h = (unsigned short*)alloc(20480 * 2);
  unsigned short* w2l = (unsigned short*)alloc(20480 * 2);
  unsigned short* w3h = (unsigned short*)alloc(5120 * 2);
  unsigned short* w3l = (unsigned short*)alloc(5120 * 2);
  unsigned short* linwh = (unsigned short*)alloc(172800 * 2);
  unsigned short* linwl = (unsigned short*)alloc(172800 * 2);
  unsigned short* wih0h = (unsigned short*)alloc(65536 * 2);
  unsigned short* wih0l = (unsigned short*)alloc(65536 * 2);
  unsigned short* wih1h = (unsigned short*)alloc(65536 * 2);
  unsigned short* wih1l = (unsigned short*)alloc(65536 * 2);
  float* whh0T = (float*)alloc(65536 * 4);
  float* wih1T = (float*)alloc(65536 * 4);
  float* whh1T = (float*)alloc(65536 * 4);

  hipMemsetAsync(flags, 0, 32 * sizeof(int), stream);
  k_prep<<<2059, 256, 0, stream>>>(w1, w2, w3, linw, wih0, whh0, wih1, whh1,
                                   w1eh, w1el, w2h, w2l, w3h, w3l,
                                   linwh, linwl, wih0h, wih0l, wih1h, wih1l,
                                   whh0T, wih1T, whh1T);
  k_conv123<<<2048, 512, 0, stream>>>(X, w1, w2h, w2l, w3h, w3l, s3g);
  k_gemm_fx<<<128, 448, 0, stream>>>(s3g, linwh, linwl, wih0h, wih0l, xg0);
  k_lstm_fused<<<64, 512, 0, stream>>>(xg0, whh0T, whh1T, wih1h, wih1l,
                                       fc1, fc2, lengths, xg1, flags,
                                       (float*)d_out);
}